// Round 3
// baseline (3383.681 us; speedup 1.0000x reference)
//
#include <hip/hip_runtime.h>
#include <stdint.h>

#define TT 2048
#define BB 128
#define DD 100
#define HH 100
#define GG 300   // 3*H, PyTorch gate order [r,z,n]
#define NT 31
#define NEGV (-10000.0f)

// ---------------------------------------------------------------------------
// Kernel 1: gi[dir][t][g] = x_dir(t) @ w_ih^T + b_ih  for batch row `seq`.
// ---------------------------------------------------------------------------
__global__ __launch_bounds__(320) void gi_kernel(
    const float* __restrict__ sent, const int* __restrict__ seqp,
    const float* __restrict__ w_ih_f, const float* __restrict__ b_ih_f,
    const float* __restrict__ w_ih_b, const float* __restrict__ b_ih_b,
    float* __restrict__ gi)
{
    const int t   = blockIdx.x;
    const int dir = blockIdx.y;
    const int j   = threadIdx.x;
    const int seq = seqp[0];
    const int ts  = dir ? (TT - 1 - t) : t;
    __shared__ __align__(16) float x_s[DD];
    if (j < DD) x_s[j] = sent[((size_t)ts * BB + seq) * DD + j];
    __syncthreads();
    if (j < GG) {
        const float* w = dir ? w_ih_b : w_ih_f;
        const float* b = dir ? b_ih_b : b_ih_f;
        const float4* w4 = (const float4*)(w + j * DD);
        const float4* x4 = (const float4*)x_s;
        float a0 = 0.f, a1 = 0.f, a2 = 0.f, a3 = 0.f;
        #pragma unroll
        for (int k = 0; k < DD / 4; k++) {
            float4 wv = w4[k], xv = x4[k];
            a0 += wv.x * xv.x; a1 += wv.y * xv.y;
            a2 += wv.z * xv.z; a3 += wv.w * xv.w;
        }
        gi[((size_t)dir * TT + t) * GG + j] = b[j] + (a0 + a1) + (a2 + a3);
    }
}

// float4 component by compile-time index (keeps arrays in registers / SROA)
#define WCOMP(arr, k) (((k) & 3) == 0 ? (arr)[(k) >> 2].x : \
                       ((k) & 3) == 1 ? (arr)[(k) >> 2].y : \
                       ((k) & 3) == 2 ? (arr)[(k) >> 2].z : (arr)[(k) >> 2].w)

// broadcast h[k] from the wave's own float2 copy via v_readlane -> SGPR
#define RLH(k) __int_as_float(__builtin_amdgcn_readlane( \
                  __float_as_int(((k) & 1) ? hp.y : hp.x), (k) >> 1))

#define DOT_CHUNK(c, BOTH)                                               \
    _Pragma("unroll")                                                    \
    for (int k8 = 0; k8 < 25; k8++) {                                    \
        const int k = (c) * 25 + k8;                                     \
        float hk = RLH(k);                                               \
        if (k & 1) a1 = fmaf(hk, WCOMP(wp4, k), a1);                     \
        else       a0 = fmaf(hk, WCOMP(wp4, k), a0);                     \
        if (BOTH) {                                                      \
            if (k & 1) c1 = fmaf(hk, WCOMP(ws4, k), c1);                 \
            else       c0 = fmaf(hk, WCOMP(ws4, k), c0);                 \
        }                                                                \
    }

// ---------------------------------------------------------------------------
// Kernel 2: sequential GRU + fused output-projection partials.
// 256 threads (4 waves, 1 per SIMD). Broadcast of h is v_readlane -> SGPR
// (pure VALU) instead of per-thread LDS re-reads (which were the R2 pipe
// bottleneck: 150 ds_read_b128/step).
//   lane (=tid)        : primary gate row tid (0..255), W_hh row in VGPRs
//   lanes 128..171     : secondary gate rows 256..299
//   lanes 172..202     : secondary w_out rows 0..30 (pfeat, 1-step delayed,
//                        global stores batched every 8 steps)
// ---------------------------------------------------------------------------
__global__ __launch_bounds__(256, 1) void gru_seq_kernel(
    const float* __restrict__ gi,
    const float* __restrict__ w_hh_f, const float* __restrict__ b_hh_f,
    const float* __restrict__ w_hh_b, const float* __restrict__ b_hh_b,
    const float* __restrict__ w_out,
    float* __restrict__ pfeat)           // [2][TT][NT], original time order
{
    const int dir = blockIdx.x;
    const int tid = threadIdx.x;
    const float* w_hh = dir ? w_hh_b : w_hh_f;
    const float* b_hh = dir ? b_hh_b : b_hh_f;
    const float* gid  = gi + (size_t)dir * TT * GG;
    float* pf = pfeat + (size_t)dir * TT * NT;

    const int  rp       = tid;                           // primary row
    const bool sec_gate = (tid >= 128) && (tid < 172);   // rows 256..299
    const bool sec_pf   = (tid >= 172) && (tid < 203);   // pfeat rows 0..30
    const int  rs       = 256 + (tid - 128);
    const int  pn       = tid - 172;

    __shared__ __align__(16) float h_s[2][128];
    __shared__ float s_rz[2 * HH];
    __shared__ float s_hn[HH];
    __shared__ float s_gn[HH];

    float4 wp4[25], ws4[25];
    {
        const float4* w4 = (const float4*)(w_hh + rp * DD);
        #pragma unroll
        for (int k = 0; k < 25; k++) wp4[k] = w4[k];
    }
    #pragma unroll
    for (int k = 0; k < 25; k++) ws4[k] = make_float4(0.f, 0.f, 0.f, 0.f);
    float bpr = b_hh[rp], bsr = 0.f;
    if (sec_gate) {
        const float4* w4 = (const float4*)(w_hh + rs * DD);
        #pragma unroll
        for (int k = 0; k < 25; k++) ws4[k] = w4[k];
        bsr = b_hh[rs];
    } else if (sec_pf) {
        const float4* w4 = (const float4*)(w_out + pn * (2 * HH) + dir * HH);
        #pragma unroll
        for (int k = 0; k < 25; k++) ws4[k] = w4[k];
    }
    if (tid < 128) { h_s[0][tid] = 0.f; h_s[1][tid] = 0.f; }
    __syncthreads();

    float pf_hist[8];
    float gvp_n = gid[rp];                         // prefetch t=0
    float gvs_n = sec_gate ? gid[rs] : 0.f;
    int cur = 0;

    for (int t = 0; t < TT; t++) {
        float2 hp = ((const float2*)h_s[cur])[tid & 63];   // 1 ds_read_b64/wave
        float gvp = gvp_n, gvs = gvs_n;
        if (t + 1 < TT) {
            gvp_n = gid[(t + 1) * GG + rp];
            if (sec_gate) gvs_n = gid[(t + 1) * GG + rs];
        }
        float a0 = bpr, a1 = 0.f, c0 = bsr, c1 = 0.f;
        if (tid & 128) {            // waves 2,3: both dot streams
            DOT_CHUNK(0, true)  __builtin_amdgcn_sched_barrier(0);
            DOT_CHUNK(1, true)  __builtin_amdgcn_sched_barrier(0);
            DOT_CHUNK(2, true)  __builtin_amdgcn_sched_barrier(0);
            DOT_CHUNK(3, true)
        } else {                    // waves 0,1: primary only
            DOT_CHUNK(0, false) __builtin_amdgcn_sched_barrier(0);
            DOT_CHUNK(1, false) __builtin_amdgcn_sched_barrier(0);
            DOT_CHUNK(2, false) __builtin_amdgcn_sched_barrier(0);
            DOT_CHUNK(3, false)
        }
        float accp = a0 + a1, accs = c0 + c1;
        if (rp < 2 * HH) s_rz[rp] = accp + gvp;
        else { s_hn[rp - 2 * HH] = accp; s_gn[rp - 2 * HH] = gvp; }
        if (sec_gate) { s_hn[rs - 2 * HH] = accs; s_gn[rs - 2 * HH] = gvs; }
        if (sec_pf) {
            if (t > 0) pf_hist[(t - 1) & 7] = accs;   // pfeat of h after t-1
            if (t >= 8 && (t & 7) == 0) {             // flush pf[t-8 .. t-1]
                int tb = t - 8;
                #pragma unroll
                for (int i = 0; i < 8; i++) {
                    int ot = dir ? (TT - 1 - (tb + i)) : (tb + i);
                    pf[(size_t)ot * NT + pn] = pf_hist[i];
                }
            }
        }
        __syncthreads();
        if (tid < HH) {
            float r   = 1.f / (1.f + __expf(-s_rz[tid]));
            float z   = 1.f / (1.f + __expf(-s_rz[HH + tid]));
            float pre = s_gn[tid] + r * s_hn[tid];
            pre = fmaxf(fminf(pre, 40.f), -40.f);
            float e2  = __expf(-2.f * pre);
            float nn  = (1.f - e2) / (1.f + e2);
            h_s[cur ^ 1][tid] = (1.f - z) * nn + z * h_s[cur][tid];
        }
        __syncthreads();
        cur ^= 1;
    }

    // epilogue: pfeat for t = TT-1 from final h, then flush last 8
    {
        float2 hp = ((const float2*)h_s[cur])[tid & 63];
        float a0 = 0.f, a1 = 0.f, c0 = 0.f, c1 = 0.f;
        if (tid & 128) {
            DOT_CHUNK(0, true)  __builtin_amdgcn_sched_barrier(0);
            DOT_CHUNK(1, true)  __builtin_amdgcn_sched_barrier(0);
            DOT_CHUNK(2, true)  __builtin_amdgcn_sched_barrier(0);
            DOT_CHUNK(3, true)
        }
        (void)a0; (void)a1;
        if (sec_pf) {
            pf_hist[7] = c0 + c1;
            int tb = TT - 8;
            #pragma unroll
            for (int i = 0; i < 8; i++) {
                int ot = dir ? (TT - 1 - (tb + i)) : (tb + i);
                pf[(size_t)ot * NT + pn] = pf_hist[i];
            }
        }
    }
}

// ---------------------------------------------------------------------------
// Kernel 3: Viterbi. Single wave. fv[p] broadcast via v_readlane -> SGPR
// (pure VALU, no bpermute storm). Exact first-max via 4 ordered streams with
// strict '>' updates. Backpointers packed 4/u32, stride 513 (bank-clean).
// Composed 64-step maps (1 shfl/step) => 32-way parallel backtrack.
// ---------------------------------------------------------------------------
__global__ __launch_bounds__(64) void viterbi_kernel(
    const float* __restrict__ pfeat, const float* __restrict__ mask,
    const int* __restrict__ seqp, const float* __restrict__ trans,
    const float* __restrict__ b_out, float* __restrict__ out)
{
    const int lane = threadIdx.x;
    const bool act = (lane < NT);
    const float* mrow = mask + (size_t)seqp[0] * TT;
    const float* pff = pfeat;
    const float* pfb = pfeat + (size_t)TT * NT;

    __shared__ uint32_t bp4[NT * 513];   // 63612 B
    __shared__ uint8_t  gchk[32 * 32];
    __shared__ uint8_t  echk[32];

    float tr[NT];
    #pragma unroll
    for (int p = 0; p < NT; p++)
        tr[p] = act ? trans[lane * NT + p] : -3.0e38f;
    float bo = act ? b_out[lane] : 0.f;

    float fv = (lane == 0) ? 0.f : NEGV;
    int   G  = lane & 31;
    uint32_t bpw = 0;

    float f_cur = act ? (pff[lane] + pfb[lane] + bo) : 0.f;
    float m_cur = mrow[0];
    float ffn = 0.f, fbn = 0.f, mn = 0.f;

    for (int t = 0; t < TT; t++) {
        if (t + 1 < TT) {
            if (act) { ffn = pff[(t + 1) * NT + lane]; fbn = pfb[(t + 1) * NT + lane]; }
            mn = mrow[t + 1];
        }
        float b0 = -3.0e38f, b1 = -3.0e38f, b2 = -3.0e38f, b3 = -3.0e38f;
        int   i0 = 0, i1 = 0, i2 = 0, i3 = 0;
        #pragma unroll
        for (int p = 0; p < NT; p++) {
            float s = __int_as_float(__builtin_amdgcn_readlane(__float_as_int(fv), p)) + tr[p];
            if (p < 8)       { if (s > b0) { b0 = s; i0 = p; } }
            else if (p < 16) { if (s > b1) { b1 = s; i1 = p; } }
            else if (p < 24) { if (s > b2) { b2 = s; i2 = p; } }
            else             { if (s > b3) { b3 = s; i3 = p; } }
        }
        float best = b0; int bi = i0;             // strict '>' keeps lowest p
        if (b1 > best) { best = b1; bi = i1; }
        if (b2 > best) { best = b2; bi = i2; }
        if (b3 > best) { best = b3; bi = i3; }

        bool live = m_cur > 0.f;
        float fvn = live ? (best + f_cur) : fv;
        int   bpn = live ? bi : (lane & 31);
        fv = fvn;
        G = __shfl(G, bpn & 31);                  // compose map (1 bpermute)
        bpw |= (uint32_t)(bpn & 255) << (8 * (t & 3));
        if ((t & 3) == 3) {
            if (act) bp4[lane * 513 + (t >> 2)] = bpw;
            bpw = 0;
        }
        if ((t & 63) == 63) {
            if (act) gchk[(t >> 6) * 32 + lane] = (uint8_t)G;
            G = lane & 31;
        }
        f_cur = ffn + fbn + bo;
        m_cur = mn;
    }
    __syncthreads();

    // final argmax over fv[0..30], strict '>' (first-max), all lanes compute
    float fbest = __int_as_float(__builtin_amdgcn_readlane(__float_as_int(fv), 0));
    int ftag = 0;
    #pragma unroll
    for (int p = 1; p < NT; p++) {
        float s = __int_as_float(__builtin_amdgcn_readlane(__float_as_int(fv), p));
        if (s > fbest) { fbest = s; ftag = p; }
    }

    if (lane == 0) {
        out[0] = fbest;
        int tag = ftag;                            // tag at t = TT-1
        for (int b = 31; b >= 0; b--) { echk[b] = (uint8_t)tag; tag = gchk[b * 32 + tag]; }
    }
    __syncthreads();
    if (lane < 32) {                               // lane b backtracks block b
        int tag = echk[lane];
        for (int i = 63; i >= 0; i--) {
            int t = lane * 64 + i;
            out[1 + t] = (float)tag;
            tag = (int)((bp4[tag * 513 + (t >> 2)] >> (8 * (t & 3))) & 255u);
        }
    }
}

// ---------------------------------------------------------------------------
extern "C" void kernel_launch(void* const* d_in, const int* in_sizes, int n_in,
                              void* d_out, int out_size, void* d_ws, size_t ws_size,
                              hipStream_t stream) {
    const float* sent   = (const float*)d_in[0];
    const float* mask   = (const float*)d_in[1];
    const float* w_ih_f = (const float*)d_in[2];
    const float* w_hh_f = (const float*)d_in[3];
    const float* b_ih_f = (const float*)d_in[4];
    const float* b_hh_f = (const float*)d_in[5];
    const float* w_ih_b = (const float*)d_in[6];
    const float* w_hh_b = (const float*)d_in[7];
    const float* b_ih_b = (const float*)d_in[8];
    const float* b_hh_b = (const float*)d_in[9];
    const float* w_out  = (const float*)d_in[10];
    const float* b_out  = (const float*)d_in[11];
    const float* trans  = (const float*)d_in[12];
    const int*   seqp   = (const int*)d_in[14];
    float* out = (float*)d_out;

    // workspace (floats): gi[2][T][300] | pfeat[2][T][31]
    float* gi    = (float*)d_ws;
    float* pfeat = gi + (size_t)2 * TT * GG;

    gi_kernel<<<dim3(TT, 2), 320, 0, stream>>>(sent, seqp, w_ih_f, b_ih_f,
                                               w_ih_b, b_ih_b, gi);
    gru_seq_kernel<<<2, 256, 0, stream>>>(gi, w_hh_f, b_hh_f, w_hh_b, b_hh_b,
                                          w_out, pfeat);
    viterbi_kernel<<<1, 64, 0, stream>>>(pfeat, mask, seqp, trans, b_out, out);
}

// Round 4
// 2294.086 us; speedup vs baseline: 1.4750x; 1.4750x over previous
//
#include <hip/hip_runtime.h>
#include <stdint.h>

#define TT 2048
#define BB 128
#define DD 100
#define HH 100
#define GG 300   // 3*H, PyTorch gate order [r,z,n]
#define NT 31
#define NEGV (-10000.0f)
#define NSLOT 331   // 300 gate rows + 31 w_out rows

// ---------------------------------------------------------------------------
// Kernel 1: gi[dir][t][g] = x_dir(t) @ w_ih^T + b_ih  for batch row `seq`.
// ---------------------------------------------------------------------------
__global__ __launch_bounds__(320) void gi_kernel(
    const float* __restrict__ sent, const int* __restrict__ seqp,
    const float* __restrict__ w_ih_f, const float* __restrict__ b_ih_f,
    const float* __restrict__ w_ih_b, const float* __restrict__ b_ih_b,
    float* __restrict__ gi)
{
    const int t   = blockIdx.x;
    const int dir = blockIdx.y;
    const int j   = threadIdx.x;
    const int seq = seqp[0];
    const int ts  = dir ? (TT - 1 - t) : t;
    __shared__ __align__(16) float x_s[DD];
    if (j < DD) x_s[j] = sent[((size_t)ts * BB + seq) * DD + j];
    __syncthreads();
    if (j < GG) {
        const float* w = dir ? w_ih_b : w_ih_f;
        const float* b = dir ? b_ih_b : b_ih_f;
        const float4* w4 = (const float4*)(w + j * DD);
        const float4* x4 = (const float4*)x_s;
        float a0 = 0.f, a1 = 0.f, a2 = 0.f, a3 = 0.f;
        #pragma unroll
        for (int k = 0; k < DD / 4; k++) {
            float4 wv = w4[k], xv = x4[k];
            a0 += wv.x * xv.x; a1 += wv.y * xv.y;
            a2 += wv.z * xv.z; a3 += wv.w * xv.w;
        }
        gi[((size_t)dir * TT + t) * GG + j] = b[j] + (a0 + a1) + (a2 + a3);
    }
}

#define RL(v, k) __int_as_float(__builtin_amdgcn_readlane(__float_as_int(v), (k)))
#define W2C(arr, k) (((k) & 1) ? (arr)[(k) >> 1].y : (arr)[(k) >> 1].x)

// ---------------------------------------------------------------------------
// Kernel 2: sequential GRU, k-split matvec + redundant activation.
// 256 threads = 4 waves (1/SIMD). Waves 0,1 own k in [0,50) ("group A"),
// waves 2,3 own k in [50,100). Each wave redundantly computes the 50 h values
// of its own k-half in lanes 0..49 -> h broadcast is v_readlane from the
// wave's own register, h NEVER goes through LDS. Half-dot partials ping-pong
// through LDS -> ONE barrier per step. w_out rows ride along as slots
// 300..330; per-step feats go to pfeat with batched stores.
// ---------------------------------------------------------------------------
__global__ __launch_bounds__(256, 1) void gru_seq_kernel(
    const float* __restrict__ gi,
    const float* __restrict__ w_hh_f, const float* __restrict__ b_hh_f,
    const float* __restrict__ w_hh_b, const float* __restrict__ b_hh_b,
    const float* __restrict__ w_out,
    float* __restrict__ pfeat)           // [2][TT][NT], original time order
{
    const int dir  = blockIdx.x;
    const int tid  = threadIdx.x;
    const int wave = tid >> 6, lane = tid & 63;
    const int grp  = wave >> 1;          // k-half
    const int wig  = wave & 1;           // wave in group
    const int k0   = grp * 50;
    const float* w_hh = dir ? w_hh_b : w_hh_f;
    const float* b_hh = dir ? b_hh_b : b_hh_f;
    const float* gid  = gi + (size_t)dir * TT * GG;
    float* pf = pfeat + (size_t)dir * TT * NT;

    __shared__ float part[2][2 * NSLOT]; // [buf][slot*2 + half]

    // ---- weight setup: 3 slot layers, 50 floats each, in VGPRs ----
    const int s0 = wig * 64 + lane;      // layer-0 slot
    const int s2 = 256 + s0;             // layer-2 slot (may be invalid)
    float2 w0[25], w1[25], w2[25];
    {
        const float2* q0 = (const float2*)(w_hh + s0 * DD + k0);
        const float2* q1 = (const float2*)(w_hh + (128 + s0) * DD + k0);
        #pragma unroll
        for (int k = 0; k < 25; k++) { w0[k] = q0[k]; w1[k] = q1[k]; }
        #pragma unroll
        for (int k = 0; k < 25; k++) w2[k] = make_float2(0.f, 0.f);
        if (s2 < NSLOT) {
            const float2* q2 = (s2 < GG)
                ? (const float2*)(w_hh + s2 * DD + k0)
                : (const float2*)(w_out + (s2 - GG) * (2 * HH) + dir * HH + k0);
            #pragma unroll
            for (int k = 0; k < 25; k++) w2[k] = q2[k];
        }
    }

    // ---- activation setup: lane < 50 handles row r = grp*50 + lane ----
    const bool is_act = (lane < 50);
    const int  r      = grp * 50 + lane;
    float br_r = 0.f, br_z = 0.f, br_n = 0.f;
    if (is_act) { br_r = b_hh[r]; br_z = b_hh[HH + r]; br_n = b_hh[2 * HH + r]; }

    // ---- pfeat sum lanes ----
    int p = -1;
    if (lane >= 50) {
        if (wave == 0) p = lane - 50;            // 0..13
        else if (wave == 1) p = 14 + lane - 50;  // 14..27
        else if (wave == 2) p = 28 + lane - 50;  // 28..30 (lanes 50..52)
    }
    const bool is_pf = (p >= 0) && (p < NT);
    float pf_hist[8];

    float hreg = 0.f;                    // lane L: h[k0 + L] (L<50)

    // gi prefetch pipeline, depth 2
    float gAr = 0.f, gAz = 0.f, gAn = 0.f, gBr = 0.f, gBz = 0.f, gBn = 0.f;
    if (is_act) {
        gAr = gid[r];          gAz = gid[HH + r];          gAn = gid[2 * HH + r];
        gBr = gid[GG + r];     gBz = gid[GG + HH + r];     gBn = gid[GG + 2 * HH + r];
    }
    __syncthreads();

    auto do_step = [&](int t, float& cr, float& cz, float& cn) {
        const int buf = t & 1;
        // ---- phase M: half-dots of all 3 slot layers against h_{t-1} ----
        float a0 = 0.f, a1 = 0.f, a2 = 0.f;
        #pragma unroll
        for (int kk = 0; kk < 50; kk++) {
            float hk = RL(hreg, kk);
            a0 = fmaf(hk, W2C(w0, kk), a0);
            a1 = fmaf(hk, W2C(w1, kk), a1);
            a2 = fmaf(hk, W2C(w2, kk), a2);
        }
        part[buf][s0 * 2 + grp]         = a0;
        part[buf][(128 + s0) * 2 + grp] = a1;
        if (s2 < NSLOT) part[buf][s2 * 2 + grp] = a2;
        __syncthreads();
        // ---- phase A: activation (redundant per k-group) ----
        if (is_act) {
            float2 prr = *(const float2*)&part[buf][r * 2];
            float2 prz = *(const float2*)&part[buf][(HH + r) * 2];
            float2 prn = *(const float2*)&part[buf][(2 * HH + r) * 2];
            float xr  = prr.x + prr.y + br_r + cr;
            float xz  = prz.x + prz.y + br_z + cz;
            float ghn = prn.x + prn.y + br_n;
            float rr  = 1.f / (1.f + __expf(-xr));
            float zz  = 1.f / (1.f + __expf(-xz));
            float pre = cn + rr * ghn;
            pre = fmaxf(fminf(pre, 40.f), -40.f);
            float e2  = __expf(-2.f * pre);
            float nn  = (1.f - e2) / (1.f + e2);
            hreg = (1.f - zz) * nn + zz * hreg;
            // prefetch gi for t+2
            int tp = t + 2; tp = (tp < TT) ? tp : (TT - 1);
            cr = gid[tp * GG + r];
            cz = gid[tp * GG + HH + r];
            cn = gid[tp * GG + 2 * HH + r];
        }
        if (is_pf) {
            float2 pp = *(const float2*)&part[buf][(GG + p) * 2];
            if (t > 0) pf_hist[(t - 1) & 7] = pp.x + pp.y;  // feat of time t-1
            if (t >= 8 && (t & 7) == 0) {
                int tb = t - 8;
                #pragma unroll
                for (int i = 0; i < 8; i++) {
                    int ot = dir ? (TT - 1 - (tb + i)) : (tb + i);
                    pf[(size_t)ot * NT + p] = pf_hist[i];
                }
            }
        }
    };

    for (int t = 0; t < TT; t += 2) {
        do_step(t,     gAr, gAz, gAn);
        do_step(t + 1, gBr, gBz, gBn);
    }

    // epilogue: one more M phase for feat of t = TT-1 (w_out . h_{TT-1})
    {
        float a0 = 0.f, a1 = 0.f, a2 = 0.f;
        #pragma unroll
        for (int kk = 0; kk < 50; kk++) {
            float hk = RL(hreg, kk);
            a0 = fmaf(hk, W2C(w0, kk), a0);
            a1 = fmaf(hk, W2C(w1, kk), a1);
            a2 = fmaf(hk, W2C(w2, kk), a2);
        }
        part[0][s0 * 2 + grp]         = a0;
        part[0][(128 + s0) * 2 + grp] = a1;
        if (s2 < NSLOT) part[0][s2 * 2 + grp] = a2;
        __syncthreads();
        if (is_pf) {
            float2 pp = *(const float2*)&part[0][(GG + p) * 2];
            pf_hist[7] = pp.x + pp.y;                 // t' = TT-1, (TT-1)&7 == 7
            int tb = TT - 8;
            #pragma unroll
            for (int i = 0; i < 8; i++) {
                int ot = dir ? (TT - 1 - (tb + i)) : (tb + i);
                pf[(size_t)ot * NT + p] = pf_hist[i];
            }
        }
    }
}

// ---------------------------------------------------------------------------
// Kernel 3a: serial Viterbi fv scan (values only — max is FP-order-free so
// any max order is bit-exact). Single wave, zero barriers, feats prefetched
// 4 deep (covers L3/HBM latency). Stores fv_t vectors to global for the
// parallel backpointer pass. fvg[t] = fv BEFORE step t (slot 0 = init).
// ---------------------------------------------------------------------------
__global__ __launch_bounds__(64) void vit_scan_kernel(
    const float* __restrict__ pfeat, const float* __restrict__ mask,
    const int* __restrict__ seqp, const float* __restrict__ trans,
    const float* __restrict__ b_out,
    float* __restrict__ fvg, int* __restrict__ meta, float* __restrict__ out)
{
    const int lane = threadIdx.x;
    const int ln   = (lane < NT) ? lane : (NT - 1);   // clamped for loads
    const float* mrow = mask + (size_t)seqp[0] * TT;
    const float* pff = pfeat;
    const float* pfb = pfeat + (size_t)TT * NT;

    float trp[NT];
    #pragma unroll
    for (int q = 0; q < NT; q++) trp[q] = trans[ln * NT + q];
    const float bo = b_out[ln];

    float fv = (lane == 0) ? 0.f : NEGV;
    fvg[lane] = fv;                                   // slot 0 = init

    float ffr[4], fbr[4], mr[4];
    #pragma unroll
    for (int q = 0; q < 4; q++) {
        ffr[q] = pff[q * NT + ln]; fbr[q] = pfb[q * NT + ln]; mr[q] = mrow[q];
    }

    for (int t = 0; t < TT; t += 4) {
        #pragma unroll
        for (int q = 0; q < 4; q++) {
            float fcur = ffr[q] + fbr[q] + bo;
            float mcur = mr[q];
            int tp = t + q + 4; tp = (tp < TT) ? tp : (TT - 1);
            ffr[q] = pff[tp * NT + ln]; fbr[q] = pfb[tp * NT + ln]; mr[q] = mrow[tp];
            float v[NT];
            #pragma unroll
            for (int q2 = 0; q2 < NT; q2++) v[q2] = RL(fv, q2) + trp[q2];
            float m = v[0];
            #pragma unroll
            for (int q2 = 1; q2 + 1 < NT; q2 += 2)
                m = fmaxf(fmaxf(m, v[q2]), v[q2 + 1]);   // -> v_max3
            float cand = m + fcur;
            fv = (mcur > 0.f) ? cand : fv;
            fvg[(t + q + 1) * 64 + lane] = fv;
        }
    }

    // final argmax, strict '>' ascending = first-max
    float fbest = RL(fv, 0);
    int ftag = 0;
    #pragma unroll
    for (int q = 1; q < NT; q++) {
        float s = RL(fv, q);
        if (s > fbest) { fbest = s; ftag = q; }
    }
    if (lane == 0) { out[0] = fbest; meta[0] = ftag; }
}

// ---------------------------------------------------------------------------
// Kernel 3b: parallel backpointer pass. Block b: t in [64b, 64b+64), 16 waves
// x 4 t's each. Recomputes s = fv_prev[p] + tr[j][p] from the stored fv
// (bit-exact same operands as the scan) with exact first-max. Then wave 0
// composes the block's 64 backpointer maps.
// ---------------------------------------------------------------------------
__global__ __launch_bounds__(1024) void vit_bp_kernel(
    const float* __restrict__ fvg, const float* __restrict__ mask,
    const int* __restrict__ seqp, const float* __restrict__ trans,
    uint8_t* __restrict__ bpg, uint8_t* __restrict__ gmapg)
{
    const int b    = blockIdx.x;
    const int tid  = threadIdx.x;
    const int wave = tid >> 6, lane = tid & 63;
    const int j    = lane & 31;
    const int jr   = (j < NT) ? j : (NT - 1);
    const float* mrow = mask + (size_t)seqp[0] * TT;

    __shared__ int bpl[64][32];

    float trj[NT];
    #pragma unroll
    for (int q = 0; q < NT; q++) trj[q] = trans[jr * NT + q];

    #pragma unroll
    for (int q4 = 0; q4 < 4; q4++) {
        const int t = b * 64 + wave * 4 + q4;
        float fvp = fvg[t * 64 + lane];          // lane p holds fv_prev[p]
        float mcur = mrow[t];
        float best = RL(fvp, 0) + trj[0];
        int bi = 0;
        #pragma unroll
        for (int q = 1; q < NT; q++) {
            float s = RL(fvp, q) + trj[q];
            if (s > best) { best = s; bi = q; }  // ascending strict '>' = first-max
        }
        int bpn = (mcur > 0.f) ? bi : j;
        if (j == 31) bpn = 31;
        if (lane < 32) {
            bpl[wave * 4 + q4][lane] = bpn;
            if (j < NT) bpg[(size_t)t * NT + j] = (uint8_t)bpn;
        }
    }
    __syncthreads();
    if (wave == 0) {
        int G = j;
        for (int i = 0; i < 64; i++) {
            int bpv = bpl[i][j];
            G = __shfl(G, bpv);                  // G_new[j] = G_old[bp_i[j]]
        }
        if (lane < 32) gmapg[b * 32 + lane] = (uint8_t)G;
    }
}

// ---------------------------------------------------------------------------
// Kernel 3c: backtrack. Loads all backpointers into LDS, composes the 32
// block maps serially (lane 0), then 32 lanes backtrack 64 steps each.
// ---------------------------------------------------------------------------
__global__ __launch_bounds__(64) void vit_back_kernel(
    const uint8_t* __restrict__ bpg, const uint8_t* __restrict__ gmapg,
    const int* __restrict__ meta, float* __restrict__ out)
{
    const int tid = threadIdx.x;
    __shared__ uint8_t bps[TT * NT];     // 63488 B
    __shared__ uint8_t gm[32 * 32];
    __shared__ uint8_t echk[32];

    const uint32_t* src = (const uint32_t*)bpg;
    uint32_t* dst = (uint32_t*)bps;
    for (int i = tid; i < TT * NT / 4; i += 64) dst[i] = src[i];
    for (int i = tid; i < 1024 / 4; i += 64)
        ((uint32_t*)gm)[i] = ((const uint32_t*)gmapg)[i];
    __syncthreads();

    if (tid == 0) {
        int tag = meta[0];
        for (int b = 31; b >= 0; b--) { echk[b] = (uint8_t)tag; tag = gm[b * 32 + tag]; }
    }
    __syncthreads();
    if (tid < 32) {
        int tag = echk[tid];
        for (int i = 63; i >= 0; i--) {
            int t = tid * 64 + i;
            out[1 + t] = (float)tag;
            tag = bps[t * NT + tag];
        }
    }
}

// ---------------------------------------------------------------------------
extern "C" void kernel_launch(void* const* d_in, const int* in_sizes, int n_in,
                              void* d_out, int out_size, void* d_ws, size_t ws_size,
                              hipStream_t stream) {
    const float* sent   = (const float*)d_in[0];
    const float* mask   = (const float*)d_in[1];
    const float* w_ih_f = (const float*)d_in[2];
    const float* w_hh_f = (const float*)d_in[3];
    const float* b_ih_f = (const float*)d_in[4];
    const float* b_hh_f = (const float*)d_in[5];
    const float* w_ih_b = (const float*)d_in[6];
    const float* w_hh_b = (const float*)d_in[7];
    const float* b_ih_b = (const float*)d_in[8];
    const float* b_hh_b = (const float*)d_in[9];
    const float* w_out  = (const float*)d_in[10];
    const float* b_out  = (const float*)d_in[11];
    const float* trans  = (const float*)d_in[12];
    const int*   seqp   = (const int*)d_in[14];
    float* out = (float*)d_out;

    // ws layout (floats): gi[2*TT*300] | pfeat[2*TT*31] | fvg[(TT+1)*64] |
    //                     bpg (TT*31 bytes) | gmapg (1024 bytes) | meta
    float* gi    = (float*)d_ws;
    float* pfeat = gi + (size_t)2 * TT * GG;
    float* fvg   = pfeat + (size_t)2 * TT * NT;
    float* bpf   = fvg + (size_t)(TT + 1) * 64;
    uint8_t* bpg   = (uint8_t*)bpf;
    uint8_t* gmapg = bpg + (size_t)TT * NT;
    int*     meta  = (int*)(gmapg + 1024);

    gi_kernel<<<dim3(TT, 2), 320, 0, stream>>>(sent, seqp, w_ih_f, b_ih_f,
                                               w_ih_b, b_ih_b, gi);
    gru_seq_kernel<<<2, 256, 0, stream>>>(gi, w_hh_f, b_hh_f, w_hh_b, b_hh_b,
                                          w_out, pfeat);
    vit_scan_kernel<<<1, 64, 0, stream>>>(pfeat, mask, seqp, trans, b_out,
                                          fvg, meta, out);
    vit_bp_kernel<<<32, 1024, 0, stream>>>(fvg, mask, seqp, trans, bpg, gmapg);
    vit_back_kernel<<<1, 64, 0, stream>>>(bpg, gmapg, meta, out);
}